// Round 6
// baseline (163.235 us; speedup 1.0000x reference)
//
#include <hip/hip_runtime.h>
#include <stdint.h>

// ContrastiveLossInBatch: loss = mean_i [ lse_j(q_i.k_j/T) - q_i.k_i/T ],
// N=8192, C=256, T=0.07.
//
// R6 = R5 + compile fix (cvt_pkrtz returns __fp16x2; bit-cast to _Float16x2).
// SINGLE kernel (launch-node overhead ~15us/node dominated the total).
// - fp32->f16 conversion inlined: q per-wave at start (QS folded), k during
//   staging (global fp32 -> pkrtz -> ds_write_b128, same XOR-swizzled layout).
// - finish fused via completion counters in poisoned ws (0xAA pattern known):
//   last sp-block per rb merges its 128 rows; 64th rb-finisher writes out[0].
//
// Workspace: pM/pS/pP (SPLIT*N floats each), part[64], cntRb[64], cntAll[1].

#define N_ROWS 8192
#define C_DIM  256
#define BM     128                // rows per block; wave owns 32 (2 groups of 16)
#define BN     64
#define SPLIT  8
#define JCOLS  (N_ROWS / SPLIT)   // 1024 columns per split
#define JTILES (JCOLS / BN)       // 16 k-tiles per split
#define TILE_B (BN * C_DIM * 2)   // 32 KiB f16 per k-tile in LDS
#define TILE_F (BN * C_DIM)       // floats per fp32 k-tile
#define SKIP_D 24.0f
#define POISON 0xAAAAAAAAu
#define QS     20.60992915555663f // (1/0.07) * log2(e)

typedef __attribute__((ext_vector_type(8))) _Float16 half8;
typedef __attribute__((ext_vector_type(2))) _Float16 half2v;
typedef __attribute__((ext_vector_type(4))) float    f32x4;

#if __has_builtin(__builtin_amdgcn_exp2f)
#define EXP2(x) __builtin_amdgcn_exp2f(x)
#else
#define EXP2(x) exp2f(x)
#endif
#if __has_builtin(__builtin_amdgcn_logf)
#define LOG2(x) __builtin_amdgcn_logf(x)
#else
#define LOG2(x) log2f(x)
#endif

__device__ __forceinline__ half2v pkrtz(float a, float b) {
#if __has_builtin(__builtin_amdgcn_cvt_pkrtz)
  return __builtin_bit_cast(half2v, __builtin_amdgcn_cvt_pkrtz(a, b));
#else
  half2v r; r[0] = (_Float16)a; r[1] = (_Float16)b; return r;
#endif
}

__launch_bounds__(256, 2)
__global__ void fused_kernel(const float* __restrict__ q,
                             const float* __restrict__ k,
                             float* __restrict__ pM,
                             float* __restrict__ pS,
                             float* __restrict__ pP,
                             float* __restrict__ part,
                             unsigned* __restrict__ cntRb,
                             unsigned* __restrict__ cntAll,
                             float* __restrict__ out) {
  __shared__ __align__(16) _Float16 kt[2 * BN * C_DIM];  // 64 KiB (2 buffers)
  __shared__ int lastFlag;
  __shared__ float wred[4];

  const int tid  = threadIdx.x;
  const int lane = tid & 63;
  const int wave = tid >> 6;
  const int l15  = lane & 15;
  const int lg   = lane >> 4;

  const int blk  = blockIdx.x;
  const int sp   = blk & 7;         // split: & 7 -> same-sp blocks share an XCD (heuristic)
  const int rb   = blk >> 3;        // row block 0..63
  const int row0 = rb * BM + wave * 32;

  // ---- A fragments from fp32 q, QS folded, converted once -----------------
  half8 afrag[2][8];
#pragma unroll
  for (int g = 0; g < 2; ++g) {
    const float* qr = q + (size_t)(row0 + g * 16 + l15) * C_DIM + lg * 8;
#pragma unroll
    for (int f = 0; f < 8; ++f) {
      float4 a = *(const float4*)(qr + f * 32);
      float4 b = *(const float4*)(qr + f * 32 + 4);
      half2v t0 = pkrtz(a.x * QS, a.y * QS);
      half2v t1 = pkrtz(a.z * QS, a.w * QS);
      half2v t2 = pkrtz(b.x * QS, b.y * QS);
      half2v t3 = pkrtz(b.z * QS, b.w * QS);
      half8 h;
      h[0] = t0[0]; h[1] = t0[1]; h[2] = t1[0]; h[3] = t1[1];
      h[4] = t2[0]; h[5] = t2[1]; h[6] = t3[0]; h[7] = t3[1];
      afrag[g][f] = h;
    }
  }

  // Per-lane LSE state: row = row0 + g*16 + lg*4 + r, cols {cf*16+l15}
  float M[2][4], S[2][4], P[2][4];
#pragma unroll
  for (int g = 0; g < 2; ++g)
#pragma unroll
    for (int r = 0; r < 4; ++r) {
      M[g][r] = -__builtin_inff(); S[g][r] = 0.f; P[g][r] = -__builtin_inff();
    }

  // read-side swizzled base per col-frag: addr = buf + (bbase[cf] ^ (ks*64))
  int bbase[4];
#pragma unroll
  for (int cf = 0; cf < 4; ++cf) {
    int nl = cf * 16 + l15;
    bbase[cf] = nl * 512 + (((nl & 31) * 16) ^ (lg * 16));
  }

  // staging geometry: chunk i -> LDS linear (straight), global fp32 offset
  // LDS(row,c) holds global(row, c^(row&31)); write side needs no xor.
  int foff[8];
#pragma unroll
  for (int i = 0; i < 8; ++i) {
    int lin = i * 4096 + tid * 16;
    int row = lin >> 9;
    int c16 = (lin >> 4) & 31;
    int gc  = c16 ^ (row & 31);
    foff[i] = row * C_DIM + gc * 8;   // float offset into fp32 tile
  }

  const float* ks0 = k + (size_t)sp * JCOLS * C_DIM;
  char* lds = (char*)kt;
  float4 stg[16];                     // fp32 prefetch regs (one tile)

#define LOADT(JT)                                                        \
  do {                                                                   \
    const float* tb = ks0 + (size_t)(JT) * TILE_F;                       \
    _Pragma("unroll")                                                    \
    for (int i = 0; i < 8; ++i) {                                        \
      stg[2 * i]     = *(const float4*)(tb + foff[i]);                   \
      stg[2 * i + 1] = *(const float4*)(tb + foff[i] + 4);               \
    }                                                                    \
  } while (0)

#define CVTW(BUF)                                                        \
  do {                                                                   \
    char* dst = lds + (BUF) * TILE_B;                                    \
    _Pragma("unroll")                                                    \
    for (int i = 0; i < 8; ++i) {                                        \
      half2v t0 = pkrtz(stg[2*i].x,   stg[2*i].y);                       \
      half2v t1 = pkrtz(stg[2*i].z,   stg[2*i].w);                       \
      half2v t2 = pkrtz(stg[2*i+1].x, stg[2*i+1].y);                     \
      half2v t3 = pkrtz(stg[2*i+1].z, stg[2*i+1].w);                     \
      half8 h;                                                           \
      h[0]=t0[0]; h[1]=t0[1]; h[2]=t1[0]; h[3]=t1[1];                    \
      h[4]=t2[0]; h[5]=t2[1]; h[6]=t3[0]; h[7]=t3[1];                    \
      *(half8*)(dst + i * 4096 + tid * 16) = h;                          \
    }                                                                    \
  } while (0)

  // ---- prologue: tile0 -> buf0; tile1 -> regs ------------------------------
  LOADT(0);
  CVTW(0);
  LOADT(1);
  __syncthreads();

  for (int jt = 0; jt < JTILES; ++jt) {
    const char* buf = lds + (jt & 1) * TILE_B;

    f32x4 acc[2][4];
#pragma unroll
    for (int g = 0; g < 2; ++g)
#pragma unroll
      for (int cf = 0; cf < 4; ++cf) { f32x4 z = {0.f,0.f,0.f,0.f}; acc[g][cf] = z; }

#pragma unroll
    for (int ks = 0; ks < 8; ++ks)
#pragma unroll
      for (int cf = 0; cf < 4; ++cf) {
        half8 b = *(const half8*)(buf + (bbase[cf] ^ (ks * 64)));
        acc[0][cf] = __builtin_amdgcn_mfma_f32_16x16x32_f16(afrag[0][ks], b, acc[0][cf], 0, 0, 0);
        acc[1][cf] = __builtin_amdgcn_mfma_f32_16x16x32_f16(afrag[1][ks], b, acc[1][cf], 0, 0, 0);
      }

    const int j0 = sp * JCOLS + jt * BN;

#pragma unroll
    for (int g = 0; g < 2; ++g) {
      // diag capture (wave-uniform-rare branch)
      const int rg0 = row0 + g * 16;
      if (rg0 >= j0 && rg0 < j0 + BN) {
#pragma unroll
        for (int r = 0; r < 4; ++r) {
          int d = rg0 - j0 + lg * 4 + r;
#pragma unroll
          for (int cf = 0; cf < 4; ++cf)
            if (cf * 16 + l15 == d) P[g][r] = acc[g][cf][r];
        }
      }
      // per-lane online logsumexp (base 2), skip-guarded
#pragma unroll
      for (int r = 0; r < 4; ++r) {
        float v0 = acc[g][0][r], v1 = acc[g][1][r], v2 = acc[g][2][r], v3 = acc[g][3][r];
        float tmax = fmaxf(fmaxf(v0, v1), fmaxf(v2, v3));
        if (__any(tmax > M[g][r] - SKIP_D)) {
          float newM  = fmaxf(M[g][r], tmax);
          float alpha = EXP2(M[g][r] - newM);
          float p = EXP2(v0 - newM) + EXP2(v1 - newM) +
                    EXP2(v2 - newM) + EXP2(v3 - newM);
          S[g][r] = fmaf(S[g][r], alpha, p);
          M[g][r] = newM;
        }
      }
    }

    // stage tile jt+1 into the other buffer; prefetch tile jt+2
    if (jt + 1 < JTILES) CVTW((jt + 1) & 1);
    if (jt + 2 < JTILES) LOADT(jt + 2);
    __syncthreads();
  }

  // ---- 16-lane butterfly merge of (M,S), max-merge of P -------------------
#pragma unroll
  for (int g = 0; g < 2; ++g)
#pragma unroll
    for (int r = 0; r < 4; ++r) {
#pragma unroll
      for (int off = 1; off < 16; off <<= 1) {
        float Mo = __shfl_xor(M[g][r], off);
        float So = __shfl_xor(S[g][r], off);
        float nm = fmaxf(M[g][r], Mo);
        S[g][r] = S[g][r] * EXP2(M[g][r] - nm) + So * EXP2(Mo - nm);
        M[g][r] = nm;
        P[g][r] = fmaxf(P[g][r], __shfl_xor(P[g][r], off));
      }
    }

  if (l15 == 0) {
#pragma unroll
    for (int g = 0; g < 2; ++g)
#pragma unroll
      for (int r = 0; r < 4; ++r) {
        int grow = row0 + g * 16 + lg * 4 + r;
        pM[(size_t)sp * N_ROWS + grow] = M[g][r];
        pS[(size_t)sp * N_ROWS + grow] = S[g][r];
        pP[(size_t)sp * N_ROWS + grow] = P[g][r];
      }
  }

  // ---- fused finish: last sp-block per rb merges this rb's 128 rows -------
  __threadfence();                       // release pM/pS/pP (all threads)
  __syncthreads();
  if (tid == 0)
    lastFlag = (atomicAdd(&cntRb[rb], 1u) == POISON + (unsigned)(SPLIT - 1));
  __syncthreads();
  if (lastFlag) {
    __threadfence();                     // acquire other blocks' pM/pS/pP
    float partial = 0.f;
    if (tid < BM) {
      int r = rb * BM + tid;
      float m = -__builtin_inff();
#pragma unroll
      for (int s = 0; s < SPLIT; ++s) m = fmaxf(m, pM[s * N_ROWS + r]);
      float ssum = 0.f;
      float pos  = -__builtin_inff();
#pragma unroll
      for (int s = 0; s < SPLIT; ++s) {
        ssum = fmaf(pS[s * N_ROWS + r], EXP2(pM[s * N_ROWS + r] - m), ssum);
        pos = fmaxf(pos, pP[s * N_ROWS + r]);
      }
      partial = (m + LOG2(ssum)) - pos;  // row loss, base-2 units
    }
#pragma unroll
    for (int off = 1; off < 64; off <<= 1) partial += __shfl_xor(partial, off);
    if (lane == 0) wred[wave] = partial;
    __syncthreads();
    if (tid == 0) {
      part[rb] = wred[0] + wred[1] + wred[2] + wred[3];
      __threadfence();                   // release part[rb]
      if (atomicAdd(cntAll, 1u) == POISON + 63u) {
        __threadfence();                 // acquire all part[]
        float s = 0.f;
#pragma unroll
        for (int i = 0; i < 64; ++i) s += part[i];
        out[0] = s * (0.69314718055994531f / (float)N_ROWS);  // ln2 * mean
      }
    }
  }
}

extern "C" void kernel_launch(void* const* d_in, const int* in_sizes, int n_in,
                              void* d_out, int out_size, void* d_ws, size_t ws_size,
                              hipStream_t stream) {
  const float* q = (const float*)d_in[0];
  const float* k = (const float*)d_in[1];
  float* out = (float*)d_out;
  char* ws = (char*)d_ws;

  float* pM = (float*)ws;                       // SPLIT*N floats
  float* pS = pM + SPLIT * N_ROWS;
  float* pP = pS + SPLIT * N_ROWS;
  float* part = pP + SPLIT * N_ROWS;            // 64 floats
  unsigned* cntRb  = (unsigned*)(part + 64);    // 64 counters (start 0xAAAAAAAA)
  unsigned* cntAll = cntRb + 64;                // 1 counter

  fused_kernel<<<dim3((N_ROWS / BM) * SPLIT), dim3(256), 0, stream>>>(
      q, k, pM, pS, pP, part, cntRb, cntAll, out);
}